// Round 3
// baseline (48.469 us; speedup 1.0000x reference)
//
#include <hip/hip_runtime.h>
#include <math.h>

#define E_CNT 1999
#define N_PTS 2000
#define B_CNT 8
#define M_CNT (2*E_CNT)                    // 3998 combined signed edges
#define MPAD 4096                          // padded edge count (zero-filled)
#define WS_STRIDE 32                       // acc padded to 128B per sample
#define NTILES 16                          // 256-row tiles over MPAD
#define NTP 136                            // upper-triangle tile pairs
#define NQ 4                               // 64-col quarters per tile
#define BLOCKS_PER_B (NTP*NQ)              // 544

#define CEXP  (-5.7707801635558535f)       // -4 * log2(e)
#define NEG2C (11.541560327111707f)        // -2 * CEXP

// Precompute combined-edge data for all samples to global scratch:
//   ecu[2*(b*MPAD+p)+0] = (cx, cy, cz, CEXP*|c|^2)
//   ecu[2*(b*MPAD+p)+1] = (ux, uy, uz, w)   w = +l (X edge) or -l (target edge)
// Also accumulates per-sample diagonal (sum l^2 over both measures) + SRNF term.
__global__ __launch_bounds__(256) void pre_kernel(
    const float* __restrict__ outp, const float* __restrict__ tgtp,
    const float* __restrict__ tmpl, float4* __restrict__ ecu,
    float* __restrict__ acc)
{
    int b = blockIdx.x >> 4;
    int p = ((blockIdx.x & 15) << 8) + threadIdx.x;   // 0..4095

    float val = 0.f;
    float4 C = make_float4(0.f, 0.f, 0.f, 0.f);
    float4 U = make_float4(0.f, 0.f, 0.f, 0.f);

    if (p < M_CNT) {
        float ax, ay, az, bx, by, bz;
        bool isX = (p < E_CNT);
        if (isX) {
            const float* o0 = outp + ((size_t)b * N_PTS + p) * 3;
            const float* t0 = tmpl + (size_t)p * 3;
            ax = o0[0] + t0[0]; ay = o0[1] + t0[1]; az = o0[2] + t0[2];
            bx = o0[3] + t0[3]; by = o0[4] + t0[4]; bz = o0[5] + t0[5];
        } else {
            int e = p - E_CNT;
            const float* g0 = tgtp + ((size_t)b * N_PTS + e) * 3;
            ax = g0[0]; ay = g0[1]; az = g0[2];
            bx = g0[3]; by = g0[4]; bz = g0[5];
        }
        float cx = 0.5f * (ax + bx), cy = 0.5f * (ay + by), cz = 0.5f * (az + bz);
        float tx = bx - ax, ty = by - ay, tz = bz - az;
        float l = sqrtf(tx * tx + ty * ty + tz * tz + 1e-12f);
        float rl = 1.0f / l;
        float w = isX ? l : -l;
        C = make_float4(cx, cy, cz, CEXP * (cx * cx + cy * cy + cz * cz));
        U = make_float4(tx * rl, ty * rl, tz * rl, w);
        val = l * l;
        if (isX) {
            const float* t0 = tmpl + (size_t)p * 3;
            float txT = t0[3] - t0[0], tyT = t0[4] - t0[1], tzT = t0[5] - t0[2];
            float lT = sqrtf(txT * txT + tyT * tyT + tzT * tzT + 1e-12f);
            float rX = rsqrtf(l), rT = rsqrtf(lT);
            float dqx = tx * rX - txT * rT;
            float dqy = ty * rX - tyT * rT;
            float dqz = tz * rX - tzT * rT;
            val += 1e-7f * (dqx * dqx + dqy * dqy + dqz * dqz);
        }
    }
    size_t base = 2 * ((size_t)b * MPAD + p);
    ecu[base]     = C;
    ecu[base + 1] = U;

    for (int off = 32; off; off >>= 1) val += __shfl_down(val, off);
    __shared__ float red[4];
    int lane = threadIdx.x & 63, wid = threadIdx.x >> 6;
    if (lane == 0) red[wid] = val;
    __syncthreads();
    if (threadIdx.x == 0)
        atomicAdd(&acc[b * WS_STRIDE], (red[0] + red[1]) + (red[2] + red[3]));
}

// Strict-upper-triangle pair sum. 64-thread blocks, R=4 rows/lane,
// 64-col chunks. Column data via wave-uniform (scalar) loads.
__global__ __launch_bounds__(64) void pair_kernel(
    const float4* __restrict__ ecu, float* __restrict__ acc)
{
    int id = blockIdx.x;
    int b = id / BLOCKS_PER_B;
    int r = id % BLOCKS_PER_B;
    int t = r >> 2, q = r & 3;
    int rt = 0, rem = t;
    while (rem >= NTILES - rt) { rem -= NTILES - rt; ++rt; }
    int ct = rt + rem;

    int lane = threadIdx.x;
    const float4* __restrict__ eb = ecu + (size_t)b * MPAD * 2;

    float4 rc[4], ru[4];
    int   ri[4];
    #pragma unroll
    for (int k = 0; k < 4; ++k) {
        int i = rt * 256 + lane + 64 * k;
        ri[k] = i;
        rc[k] = eb[2 * i];
        ru[k] = eb[2 * i + 1];
    }

    float av[4] = {0.f, 0.f, 0.f, 0.f};
    int j0 = ct * 256 + q * 64;

    if (rt != ct) {
        #pragma unroll 4
        for (int jj = 0; jj < 64; ++jj) {
            int j = j0 + jj;
            float4 cc = eb[2 * j];       // wave-uniform -> s_load
            float4 cu = eb[2 * j + 1];
            #pragma unroll
            for (int k = 0; k < 4; ++k) {
                float dc  = rc[k].x * cc.x + rc[k].y * cc.y + rc[k].z * cc.z;
                float arg = fmaf(NEG2C, dc, rc[k].w + cc.w);
                float K   = __builtin_amdgcn_exp2f(arg);
                float du  = ru[k].x * cu.x + ru[k].y * cu.y + ru[k].z * cu.z;
                av[k] = fmaf(K * du * du, cu.w, av[k]);
            }
        }
    } else {
        #pragma unroll 4
        for (int jj = 0; jj < 64; ++jj) {
            int j = j0 + jj;
            float4 cc = eb[2 * j];
            float4 cu = eb[2 * j + 1];
            #pragma unroll
            for (int k = 0; k < 4; ++k) {
                float wj  = (j > ri[k]) ? cu.w : 0.f;   // strict upper
                float dc  = rc[k].x * cc.x + rc[k].y * cc.y + rc[k].z * cc.z;
                float arg = fmaf(NEG2C, dc, rc[k].w + cc.w);
                float K   = __builtin_amdgcn_exp2f(arg);
                float du  = ru[k].x * cu.x + ru[k].y * cu.y + ru[k].z * cu.z;
                av[k] = fmaf(K * du * du, wj, av[k]);
            }
        }
    }

    float thr = av[0] * ru[0].w + av[1] * ru[1].w + av[2] * ru[2].w + av[3] * ru[3].w;
    thr *= 2.0f;
    for (int off = 32; off; off >>= 1) thr += __shfl_down(thr, off);
    if (lane == 0)
        atomicAdd(&acc[b * WS_STRIDE], thr);
}

__global__ void final_kernel(const float* __restrict__ acc, float* __restrict__ outv)
{
    float s = 0.f;
    for (int b = 0; b < B_CNT; ++b) s += acc[b * WS_STRIDE];
    outv[0] = 0.125f * s;
}

extern "C" void kernel_launch(void* const* d_in, const int* in_sizes, int n_in,
                              void* d_out, int out_size, void* d_ws, size_t ws_size,
                              hipStream_t stream)
{
    const float* outp = (const float*)d_in[0];  // (8,2000,3) f32
    const float* tgtp = (const float*)d_in[1];  // (8,2000,3) f32
    const float* tmpl = (const float*)d_in[3];  // (2000,3) f32
    float* acc = (float*)d_ws;                                   // 1 KiB
    float4* ecu = (float4*)((char*)d_ws + 1024);                 // 1 MiB edge data

    hipMemsetAsync(d_ws, 0, B_CNT * WS_STRIDE * sizeof(float), stream);
    pre_kernel<<<B_CNT * 16, 256, 0, stream>>>(outp, tgtp, tmpl, ecu, acc);
    pair_kernel<<<B_CNT * BLOCKS_PER_B, 64, 0, stream>>>(ecu, acc);
    final_kernel<<<1, 1, 0, stream>>>(acc, (float*)d_out);
}

// Round 4
// 38.317 us; speedup vs baseline: 1.2649x; 1.2649x over previous
//
#include <hip/hip_runtime.h>
#include <math.h>

#define E_CNT 1999
#define N_PTS 2000
#define B_CNT 8
#define M_CNT (2*E_CNT)                    // 3998 combined signed edges
#define MPAD 4096                          // padded (zero-filled) edge count
#define WS_STRIDE 32                       // acc padded to 128B per sample
#define NTILES 16                          // 256-row tiles over MPAD
#define NTP 136                            // upper-triangle tile pairs

#define CEXP  (-5.7707801635558535f)       // -4 * log2(e)
#define NEG2C (11.541560327111707f)        // -2 * CEXP

// Per edge p of sample b, store two float4:
//   ecu[2*(b*MPAD+p)+0] = (cx, cy, cz, B)   B = CEXP*|c|^2
//   ecu[2*(b*MPAD+p)+1] = (ux*sqrt(l), uy*sqrt(l), uz*sqrt(l), s)  s = +-1, 0 for pad
// Also accumulate per-sample diagonal sum(l^2) + SRNF term.
__global__ __launch_bounds__(256) void pre_kernel(
    const float* __restrict__ outp, const float* __restrict__ tgtp,
    const float* __restrict__ tmpl, float4* __restrict__ ecu,
    float* __restrict__ acc)
{
    int b = blockIdx.x >> 4;
    int p = ((blockIdx.x & 15) << 8) + threadIdx.x;   // 0..4095

    float val = 0.f;
    float4 C = make_float4(0.f, 0.f, 0.f, 0.f);
    float4 U = make_float4(0.f, 0.f, 0.f, 0.f);

    if (p < M_CNT) {
        float ax, ay, az, bx, by, bz;
        bool isX = (p < E_CNT);
        if (isX) {
            const float* o0 = outp + ((size_t)b * N_PTS + p) * 3;
            const float* t0 = tmpl + (size_t)p * 3;
            ax = o0[0] + t0[0]; ay = o0[1] + t0[1]; az = o0[2] + t0[2];
            bx = o0[3] + t0[3]; by = o0[4] + t0[4]; bz = o0[5] + t0[5];
        } else {
            int e = p - E_CNT;
            const float* g0 = tgtp + ((size_t)b * N_PTS + e) * 3;
            ax = g0[0]; ay = g0[1]; az = g0[2];
            bx = g0[3]; by = g0[4]; bz = g0[5];
        }
        float cx = 0.5f * (ax + bx), cy = 0.5f * (ay + by), cz = 0.5f * (az + bz);
        float tx = bx - ax, ty = by - ay, tz = bz - az;
        float l2 = tx * tx + ty * ty + tz * tz + 1e-12f;
        float l  = sqrtf(l2);
        float rs = rsqrtf(l);                 // 1/sqrt(l)
        // u*sqrt(l) = t/sqrt(l)
        C = make_float4(cx, cy, cz, CEXP * (cx * cx + cy * cy + cz * cz));
        U = make_float4(tx * rs, ty * rs, tz * rs, isX ? 1.f : -1.f);
        val = l * l;
        if (isX) {
            const float* t0 = tmpl + (size_t)p * 3;
            float txT = t0[3] - t0[0], tyT = t0[4] - t0[1], tzT = t0[5] - t0[2];
            float lT = sqrtf(txT * txT + tyT * tyT + tzT * tzT + 1e-12f);
            float rT = rsqrtf(lT);
            float dqx = tx * rs - txT * rT;   // q = t/sqrt(l)
            float dqy = ty * rs - tyT * rT;
            float dqz = tz * rs - tzT * rT;
            val += 1e-7f * (dqx * dqx + dqy * dqy + dqz * dqz);
        }
    }
    size_t base = 2 * ((size_t)b * MPAD + p);
    ecu[base]     = C;
    ecu[base + 1] = U;

    for (int off = 32; off; off >>= 1) val += __shfl_down(val, off);
    __shared__ float red[4];
    int lane = threadIdx.x & 63, wid = threadIdx.x >> 6;
    if (lane == 0) red[wid] = val;
    __syncthreads();
    if (threadIdx.x == 0)
        atomicAdd(&acc[b * WS_STRIDE], (red[0] + red[1]) + (red[2] + red[3]));
}

// Strict-upper-triangle pair sum over combined signed edges (x2 at the end).
// Block = 256x256 tile pair. 4 waves share the LDS column tile; each wave
// owns a 64-col quarter; each lane owns 4 rows (R=4) -> 2 ds_read_b128
// serve 256 pairs. Per pair: 9 VALU + 1 exp2.
__global__ __launch_bounds__(256) void pair_kernel(
    const float4* __restrict__ ecu, float* __restrict__ acc)
{
    __shared__ float4 sC[256];   // (cx, cy, cz, KW = s*exp2(B))
    __shared__ float4 sU[256];   // (ux*sl, uy*sl, uz*sl, -)
    __shared__ float  red[4];

    int id = blockIdx.x;
    int b = id / NTP;
    int t = id % NTP;
    int rt = 0, rem = t;
    while (rem >= NTILES - rt) { rem -= NTILES - rt; ++rt; }
    int ct = rt + rem;

    int tid  = threadIdx.x;
    int lane = tid & 63, w = tid >> 6;
    const float4* __restrict__ eb = ecu + (size_t)b * MPAD * 2;

    // stage 256-column tile (one column per thread)
    {
        int cj = ct * 256 + tid;
        float4 C = eb[2 * cj];
        float4 U = eb[2 * cj + 1];
        float kw = U.w * __builtin_amdgcn_exp2f(C.w);   // s_j * exp2(B_j)
        sC[tid] = make_float4(C.x, C.y, C.z, kw);
        sU[tid] = U;
    }

    // 4 rows per lane (registers)
    float chx[4], chy[4], chz[4], rB[4], rs4[4];
    float4 ru[4];
    int ri[4];
    #pragma unroll
    for (int k = 0; k < 4; ++k) {
        int i = rt * 256 + k * 64 + lane;
        ri[k] = i;
        float4 C = eb[2 * i];
        float4 U = eb[2 * i + 1];
        chx[k] = NEG2C * C.x; chy[k] = NEG2C * C.y; chz[k] = NEG2C * C.z;
        rB[k] = C.w;
        ru[k] = U; rs4[k] = U.w;
    }
    __syncthreads();

    float av[4] = {0.f, 0.f, 0.f, 0.f};
    int jl0 = w * 64;           // this wave's quarter within the LDS tile
    int j0  = ct * 256 + jl0;   // global column index base

    if (rt != ct) {
        #pragma unroll 4
        for (int jj = 0; jj < 64; ++jj) {
            float4 cc = sC[jl0 + jj];
            float4 cu = sU[jl0 + jj];
            #pragma unroll
            for (int k = 0; k < 4; ++k) {
                float arg = fmaf(chx[k], cc.x, rB[k]);
                arg = fmaf(chy[k], cc.y, arg);
                arg = fmaf(chz[k], cc.z, arg);
                float E  = __builtin_amdgcn_exp2f(arg);
                float du = ru[k].x * cu.x;
                du = fmaf(ru[k].y, cu.y, du);
                du = fmaf(ru[k].z, cu.z, du);
                float m = du * du * cc.w;
                av[k] = fmaf(E, m, av[k]);
            }
        }
    } else {
        #pragma unroll 4
        for (int jj = 0; jj < 64; ++jj) {
            float4 cc = sC[jl0 + jj];
            float4 cu = sU[jl0 + jj];
            int j = j0 + jj;
            #pragma unroll
            for (int k = 0; k < 4; ++k) {
                float kw = (j > ri[k]) ? cc.w : 0.f;    // strict upper triangle
                float arg = fmaf(chx[k], cc.x, rB[k]);
                arg = fmaf(chy[k], cc.y, arg);
                arg = fmaf(chz[k], cc.z, arg);
                float E  = __builtin_amdgcn_exp2f(arg);
                float du = ru[k].x * cu.x;
                du = fmaf(ru[k].y, cu.y, du);
                du = fmaf(ru[k].z, cu.z, du);
                float m = du * du * kw;
                av[k] = fmaf(E, m, av[k]);
            }
        }
    }

    float thr = av[0] * rs4[0] + av[1] * rs4[1] + av[2] * rs4[2] + av[3] * rs4[3];
    thr *= 2.0f;
    for (int off = 32; off; off >>= 1) thr += __shfl_down(thr, off);
    if (lane == 0) red[w] = thr;
    __syncthreads();
    if (tid == 0)
        atomicAdd(&acc[b * WS_STRIDE], (red[0] + red[1]) + (red[2] + red[3]));
}

__global__ void final_kernel(const float* __restrict__ acc, float* __restrict__ outv)
{
    float s = 0.f;
    for (int b = 0; b < B_CNT; ++b) s += acc[b * WS_STRIDE];
    outv[0] = 0.125f * s;
}

extern "C" void kernel_launch(void* const* d_in, const int* in_sizes, int n_in,
                              void* d_out, int out_size, void* d_ws, size_t ws_size,
                              hipStream_t stream)
{
    const float* outp = (const float*)d_in[0];  // (8,2000,3) f32
    const float* tgtp = (const float*)d_in[1];  // (8,2000,3) f32
    const float* tmpl = (const float*)d_in[3];  // (2000,3) f32
    float* acc = (float*)d_ws;                                   // 1 KiB
    float4* ecu = (float4*)((char*)d_ws + 1024);                 // 1 MiB edge data

    hipMemsetAsync(d_ws, 0, B_CNT * WS_STRIDE * sizeof(float), stream);
    pre_kernel<<<B_CNT * 16, 256, 0, stream>>>(outp, tgtp, tmpl, ecu, acc);
    pair_kernel<<<B_CNT * NTP, 256, 0, stream>>>(ecu, acc);
    final_kernel<<<1, 1, 0, stream>>>(acc, (float*)d_out);
}